// Round 1
// 528.636 us; speedup vs baseline: 1.1331x; 1.1331x over previous
//
#include <hip/hip_runtime.h>
#include <hip/hip_bf16.h>

#define N_CRYST 64
#define ATOMS_PER 32
#define NN 2048
#define NBRS 20
#define EE 40960
#define CC 128
#define HIDDIM 256
#define NBASIS 128
#define NLAYERS 8
#define LMAXV 6
#define KK 19
#define MAXZV 100
#define ZDIMV 256
#define FOUR_PI_F 12.566370614359172f

typedef unsigned short ushort_t;
typedef __attribute__((ext_vector_type(8))) short short8;
typedef __attribute__((ext_vector_type(4))) float floatx4;

__device__ __forceinline__ ushort_t f2us(float f) {
    union { float f; unsigned u; } x;
    x.f = f;
    unsigned r = (x.u + 0x7fffu + ((x.u >> 16) & 1u)) >> 16;
    return (ushort_t)r;
}
__device__ __forceinline__ float us2f(unsigned u) {  // low 16 bits = bf16
    return __uint_as_float(u << 16);
}

// ---------------- lattice + positions ----------------
__global__ void k_pos(const float* __restrict__ frac, const float* __restrict__ lengths,
                      const float* __restrict__ angles, const int* __restrict__ batch,
                      float* __restrict__ pos) {
    int n = blockIdx.x * blockDim.x + threadIdx.x;
    if (n >= NN) return;
    int b = batch[n];
    float la = lengths[b * 3 + 0];
    float lb = lengths[b * 3 + 1];
    float lc = lengths[b * 3 + 2];
    const float D2R = 0.017453292519943295f;
    float aa = angles[b * 3 + 0] * D2R;
    float ab = angles[b * 3 + 1] * D2R;
    float ag = angles[b * 3 + 2] * D2R;
    float ca = cosf(aa), cb = cosf(ab), cg = cosf(ag), sg = sinf(ag);
    float v3y = (ca - cb * cg) / sg;
    float v3z = sqrtf(fmaxf(1.0f - cb * cb - v3y * v3y, 1e-8f));
    float f0 = frac[n * 3 + 0];
    float f1 = frac[n * 3 + 1];
    float f2 = frac[n * 3 + 2];
    pos[n * 3 + 0] = f0 * la + f1 * (lb * cg) + f2 * (lc * cb);
    pos[n * 3 + 1] = f1 * (lb * sg) + f2 * (lc * v3y);
    pos[n * 3 + 2] = f2 * (lc * v3z);
}

// ---------------- edge geometry ----------------
__global__ void k_edge(const int* __restrict__ ei, const float* __restrict__ pos,
                       float* __restrict__ dist, float* __restrict__ dirn,
                       float* __restrict__ Yv) {
    int e = blockIdx.x * blockDim.x + threadIdx.x;
    if (e >= EE) return;
    int s = ei[e], d = ei[EE + e];
    float vx = pos[s * 3 + 0] - pos[d * 3 + 0];
    float vy = pos[s * 3 + 1] - pos[d * 3 + 1];
    float vz = pos[s * 3 + 2] - pos[d * 3 + 2];
    float dd = sqrtf(vx * vx + vy * vy + vz * vz) + 1e-8f;
    float ix = vx / dd, iy = vy / dd, iz = vz / dd;
    dist[e] = dd;
    dirn[e * 3 + 0] = ix;
    dirn[e * 3 + 1] = iy;
    dirn[e * 3 + 2] = iz;

    float ct = iz;
    float rho = sqrtf(ix * ix + iy * iy) + 1e-12f;
    float cph = ix / rho, sph = iy / rho;
    float P0[LMAXV + 1];
    float P1[LMAXV + 1];
    P0[0] = 1.0f;
    P0[1] = ct;
    #pragma unroll
    for (int l = 2; l <= LMAXV; l++)
        P0[l] = ((2 * l - 1) * ct * P0[l - 1] - (l - 1) * P0[l - 2]) / (float)l;
    P1[0] = 0.0f;
    P1[1] = -rho;
    P1[2] = -3.0f * ct * rho;
    #pragma unroll
    for (int l = 3; l <= LMAXV; l++)
        P1[l] = ((2 * l - 1) * ct * P1[l - 1] - l * P1[l - 2]) / (float)(l - 1);

    float* Ye = Yv + (size_t)e * KK;
    Ye[0] = 0.28209479177387814f;
    #pragma unroll
    for (int l = 1; l <= LMAXV; l++) {
        float K0 = sqrtf((2 * l + 1) / FOUR_PI_F);
        float K1 = sqrtf(2.0f * (2 * l + 1) / (FOUR_PI_F * l * (l + 1)));
        Ye[3 * l - 2] = K1 * P1[l] * sph;
        Ye[3 * l - 1] = K0 * P0[l];
        Ye[3 * l]     = K1 * P1[l] * cph;
    }
}

// ---------------- CSR by source atom (layer-invariant) + permuted padded Y ----------------
__global__ void k_csr(const int* __restrict__ ei, const float* __restrict__ Yv,
                      int* __restrict__ rowptr, int* __restrict__ origid,
                      float* __restrict__ Yp) {
    int cr = blockIdx.x;  // 64 blocks x 64 threads
    int t = threadIdx.x;
    __shared__ int cnt[32], base[32];
    if (t < 32) cnt[t] = 0;
    __syncthreads();
    for (int j = t; j < 640; j += 64) {
        int a = ei[cr * 640 + j] - cr * 32;
        atomicAdd(&cnt[a], 1);
    }
    __syncthreads();
    if (t == 0) {
        int run = 0;
        for (int a = 0; a < 32; a++) {
            base[a] = run;
            rowptr[cr * 33 + a] = run;
            run += cnt[a];
        }
        rowptr[cr * 33 + 32] = run;
    }
    __syncthreads();
    if (t < 32) cnt[t] = 0;
    __syncthreads();
    for (int j = t; j < 640; j += 64) {
        int e = cr * 640 + j;
        int a = ei[e] - cr * 32;
        int slot = base[a] + atomicAdd(&cnt[a], 1);
        int p = cr * 640 + slot;
        origid[p] = e;
        float* yp = Yp + (size_t)p * 20;
        #pragma unroll
        for (int k = 0; k < KK; k++) yp[k] = Yv[(size_t)e * KK + k];
        yp[19] = 0.0f;
    }
}

// ---------------- rbf -> bf16 into A-buffer cols [128,256) (layer-invariant) ----------------
__global__ void k_rbfA(const float* __restrict__ dist, ushort_t* __restrict__ Abf) {
    int idx = blockIdx.x * blockDim.x + threadIdx.x;
    if (idx >= EE * NBASIS) return;
    int e = idx >> 7, j = idx & 127;
    const float width = 8.0f / 127.0f;
    const float invw = 127.0f / 8.0f;
    float t = (dist[e] - (float)j * width) * invw;
    Abf[(size_t)e * 256 + 128 + j] = f2us(expf(-0.5f * t * t));
}

// ---------------- weight transpose+cast ----------------
__global__ void k_wt(const float* __restrict__ W1, const float* __restrict__ Wd,
                     const float* __restrict__ W2,
                     ushort_t* __restrict__ WT1, ushort_t* __restrict__ WT2) {
    int idx = blockIdx.x * blockDim.x + threadIdx.x;
    const int n1 = NLAYERS * HIDDIM * 256;
    if (idx < n1) {
        int l = idx >> 16;
        int r = idx & 65535;
        int n = r >> 8, k = r & 255;
        float v = (k < 128) ? W1[((size_t)l * CC + k) * HIDDIM + n]
                            : Wd[((size_t)l * NBASIS + (k - 128)) * HIDDIM + n];
        WT1[idx] = f2us(v);
    } else {
        int j = idx - n1;
        if (j >= NLAYERS * CC * HIDDIM) return;
        int l = j >> 15;
        int r = j & 32767;
        int n = r >> 8, k = r & 255;
        WT2[j] = f2us(W2[((size_t)l * HIDDIM + k) * CC + n]);
    }
}

// ---------------- z @ zproj ----------------
__global__ void k_zc(const float* __restrict__ z, const float* __restrict__ zproj,
                     float* __restrict__ zc) {
    int idx = blockIdx.x * blockDim.x + threadIdx.x;
    if (idx >= N_CRYST * CC) return;
    int b = idx >> 7, c = idx & 127;
    float acc = 0.0f;
    for (int d = 0; d < ZDIMV; d++)
        acc += z[b * ZDIMV + d] * zproj[d * CC + c];
    zc[idx] = acc;
}

// ---------------- init x ----------------
__global__ void k_xinit(const int* __restrict__ atype, const int* __restrict__ batch,
                        const float* __restrict__ emb, const float* __restrict__ zc,
                        float* __restrict__ x) {
    int idx = blockIdx.x * blockDim.x + threadIdx.x;
    if (idx >= NN * KK * CC) return;
    int n = idx / (KK * CC);
    int r = idx - n * (KK * CC);
    float v = 0.0f;
    if (r < CC) v = emb[atype[n] * CC + r] + zc[batch[n] * CC + r];
    x[idx] = v;
}

// ---------------- s via CSR: thread = (atom, col-pair), x slice in registers ----------------
__global__ __launch_bounds__(256) void k_s2(const int* __restrict__ rowptr,
                                            const int* __restrict__ origid,
                                            const float* __restrict__ Yp,
                                            const float* __restrict__ x,
                                            ushort_t* __restrict__ Abf) {
    int cr = blockIdx.x >> 3;
    int cbase = (blockIdx.x & 7) * 16;
    int t = threadIdx.x;
    int a = t >> 3;
    int c2 = cbase + (t & 7) * 2;

    float2 xr[20];
    const float* xp = x + (size_t)(cr * 32 + a) * (KK * CC) + c2;
    #pragma unroll
    for (int k = 0; k < KK; k++) xr[k] = *(const float2*)(xp + k * CC);
    xr[19] = make_float2(0.f, 0.f);

    int i0 = rowptr[cr * 33 + a], i1 = rowptr[cr * 33 + a + 1];
    for (int i = i0; i < i1; i++) {
        int p = cr * 640 + i;
        const float* yp = Yp + (size_t)p * 20;
        float ax = 0.f, ay = 0.f;
        #pragma unroll
        for (int kq = 0; kq < 5; kq++) {
            float4 y = *(const float4*)(yp + kq * 4);
            float2 x0 = xr[kq * 4 + 0], x1 = xr[kq * 4 + 1];
            float2 x2 = xr[kq * 4 + 2], x3 = xr[kq * 4 + 3];
            ax += y.x * x0.x + y.y * x1.x + y.z * x2.x + y.w * x3.x;
            ay += y.x * x0.y + y.y * x1.y + y.z * x2.y + y.w * x3.y;
        }
        int e = origid[p];
        unsigned pk = (unsigned)f2us(ax) | (((unsigned)f2us(ay)) << 16);
        *(unsigned*)&Abf[(size_t)e * 256 + c2] = pk;
    }
}

// ---------------- fused GEMM1 + GEMM2 + aggregation per 4-node tile ----------------
// grid 512, block 256 (4 waves). Each wave: all 80 rows x its own 64 (G1) / 32 (G2) cols.
// acc dies at silu -> low VGPR -> 2 blocks/CU (launch_bounds(256,2)).
// Reg-prefetch of next K-chunk overlaps global latency with MFMA cluster.
// LDS 60672 B:
//   GEMM1: As[80][72] @0 (11520) | Bs[256][72] @11520 (36864) -> 48384
//   GEMM2: Hs[80][264] @0 (42240) | B2s[128][72] @42240 (18432) -> 60672
//   epi:   Ms[80][132] @0 (21120) | Ylds f32 [80][20] @21120 (6400) -> 27520
__global__ __launch_bounds__(256, 2) void k_fused(const ushort_t* __restrict__ Abf,
                                                  const ushort_t* __restrict__ WT1,
                                                  const ushort_t* __restrict__ WT2,
                                                  const float* __restrict__ Yv,
                                                  float* __restrict__ x) {
    __shared__ char smraw[60672];
    ushort_t* As  = (ushort_t*)smraw;
    ushort_t* Bs  = (ushort_t*)(smraw + 11520);
    ushort_t* Hs  = (ushort_t*)smraw;
    ushort_t* B2s = (ushort_t*)(smraw + 42240);
    ushort_t* Ms  = (ushort_t*)smraw;
    float*   Ylds = (float*)(smraw + 21120);

    const int t = threadIdx.x;
    const int w = t >> 6, lane = t & 63;
    const int quad = lane >> 4, lrow = lane & 15;
    const int e0 = blockIdx.x * 80;

    floatx4 acc[5][4];
    #pragma unroll
    for (int mi = 0; mi < 5; mi++)
        #pragma unroll
        for (int ni = 0; ni < 4; ni++) acc[mi][ni] = (floatx4){0.f, 0.f, 0.f, 0.f};

    const ushort_t* Ab = Abf + (size_t)e0 * 256;
    // A staging: 640 short8 over 256 threads (2 or 3 each)
    const int a0r = t >> 3,         ac = (t & 7) * 8;
    const int a1r = (t + 256) >> 3;
    const int a2r = (t + 512) >> 3;           // valid iff t < 128
    const int brow = t >> 3, bcol = (t & 7) * 8;

    short8 arg0, arg1, arg2, brg[8];

    // ---- prologue: chunk 0 of A and B ----
    arg0 = *(const short8*)(Ab + a0r * 256 + ac);
    arg1 = *(const short8*)(Ab + a1r * 256 + ac);
    if (t < 128) arg2 = *(const short8*)(Ab + a2r * 256 + ac);
    #pragma unroll
    for (int i = 0; i < 8; i++)
        brg[i] = *(const short8*)(WT1 + (size_t)(i * 32 + brow) * 256 + bcol);
    *(short8*)&As[a0r * 72 + ac] = arg0;
    *(short8*)&As[a1r * 72 + ac] = arg1;
    if (t < 128) *(short8*)&As[a2r * 72 + ac] = arg2;
    #pragma unroll
    for (int i = 0; i < 8; i++) *(short8*)&Bs[(i * 32 + brow) * 72 + bcol] = brg[i];
    __syncthreads();

    // ---- GEMM1 K-loop: prefetch chunk c+1 into regs, MFMA chunk c ----
    #pragma unroll
    for (int c = 0; c < 4; c++) {
        if (c < 3) {
            const int k0 = (c + 1) * 64;
            arg0 = *(const short8*)(Ab + a0r * 256 + k0 + ac);
            arg1 = *(const short8*)(Ab + a1r * 256 + k0 + ac);
            if (t < 128) arg2 = *(const short8*)(Ab + a2r * 256 + k0 + ac);
            #pragma unroll
            for (int i = 0; i < 8; i++)
                brg[i] = *(const short8*)(WT1 + (size_t)(i * 32 + brow) * 256 + k0 + bcol);
        }
        #pragma unroll
        for (int ks = 0; ks < 2; ks++) {
            const int kk = ks * 32 + quad * 8;
            short8 af[5];
            #pragma unroll
            for (int mi = 0; mi < 5; mi++)
                af[mi] = *(const short8*)&As[(mi * 16 + lrow) * 72 + kk];
            #pragma unroll
            for (int ni = 0; ni < 4; ni++) {
                short8 bf = *(const short8*)&Bs[(w * 64 + ni * 16 + lrow) * 72 + kk];
                #pragma unroll
                for (int mi = 0; mi < 5; mi++)
                    acc[mi][ni] = __builtin_amdgcn_mfma_f32_16x16x32_bf16(
                        af[mi], bf, acc[mi][ni], 0, 0, 0);
            }
        }
        __syncthreads();
        if (c < 3) {
            *(short8*)&As[a0r * 72 + ac] = arg0;
            *(short8*)&As[a1r * 72 + ac] = arg1;
            if (t < 128) *(short8*)&As[a2r * 72 + ac] = arg2;
            #pragma unroll
            for (int i = 0; i < 8; i++) *(short8*)&Bs[(i * 32 + brow) * 72 + bcol] = brg[i];
            __syncthreads();
        }
    }

    // ---- silu -> Hs; prefetch B2 chunk 0 + Y tile ----
    short8 b2rg[4];
    #pragma unroll
    for (int i = 0; i < 4; i++)
        b2rg[i] = *(const short8*)(WT2 + (size_t)(i * 32 + brow) * 256 + bcol);
    float yrg[6];
    const float* Yb = Yv + (size_t)e0 * KK;
    #pragma unroll
    for (int j = 0; j < 6; j++) {
        int i = t + j * 256;
        yrg[j] = (i < 80 * KK) ? Yb[i] : 0.f;
    }
    #pragma unroll
    for (int mi = 0; mi < 5; mi++) {
        const int row = mi * 16 + quad * 4;
        #pragma unroll
        for (int ni = 0; ni < 4; ni++) {
            const int col = w * 64 + ni * 16 + lrow;
            #pragma unroll
            for (int r = 0; r < 4; r++) {
                float v = acc[mi][ni][r];
                v = v * __builtin_amdgcn_rcpf(1.0f + __expf(-v));
                Hs[(row + r) * 264 + col] = f2us(v);
            }
        }
    }
    #pragma unroll
    for (int i = 0; i < 4; i++) *(short8*)&B2s[(i * 32 + brow) * 72 + bcol] = b2rg[i];
    __syncthreads();

    // ---- GEMM2: m = silu(h) @ W2T, K chunked over hidden 256 ----
    floatx4 macc[5][2];
    #pragma unroll
    for (int mi = 0; mi < 5; mi++)
        #pragma unroll
        for (int ni = 0; ni < 2; ni++) macc[mi][ni] = (floatx4){0.f, 0.f, 0.f, 0.f};

    #pragma unroll
    for (int c = 0; c < 4; c++) {
        if (c < 3) {
            const int k0 = (c + 1) * 64;
            #pragma unroll
            for (int i = 0; i < 4; i++)
                b2rg[i] = *(const short8*)(WT2 + (size_t)(i * 32 + brow) * 256 + k0 + bcol);
        }
        #pragma unroll
        for (int ks = 0; ks < 2; ks++) {
            const int kk = ks * 32 + quad * 8;
            short8 af[5];
            #pragma unroll
            for (int mi = 0; mi < 5; mi++)
                af[mi] = *(const short8*)&Hs[(mi * 16 + lrow) * 264 + c * 64 + kk];
            #pragma unroll
            for (int ni = 0; ni < 2; ni++) {
                short8 bf = *(const short8*)&B2s[(w * 32 + ni * 16 + lrow) * 72 + kk];
                #pragma unroll
                for (int mi = 0; mi < 5; mi++)
                    macc[mi][ni] = __builtin_amdgcn_mfma_f32_16x16x32_bf16(
                        af[mi], bf, macc[mi][ni], 0, 0, 0);
            }
        }
        __syncthreads();
        if (c < 3) {
            #pragma unroll
            for (int i = 0; i < 4; i++) *(short8*)&B2s[(i * 32 + brow) * 72 + bcol] = b2rg[i];
            __syncthreads();
        }
    }

    // ---- macc -> Ms bf16 [80][132]; Y regs -> Ylds ----
    #pragma unroll
    for (int mi = 0; mi < 5; mi++) {
        const int row = mi * 16 + quad * 4;
        #pragma unroll
        for (int ni = 0; ni < 2; ni++) {
            const int col = w * 32 + ni * 16 + lrow;
            #pragma unroll
            for (int r = 0; r < 4; r++)
                Ms[(row + r) * 132 + col] = f2us(macc[mi][ni][r]);
        }
    }
    #pragma unroll
    for (int j = 0; j < 6; j++) {
        int i = t + j * 256;
        if (i < 80 * KK) Ylds[(i / KK) * 20 + (i % KK)] = yrg[j];
    }
    if (t < 80) Ylds[t * 20 + 19] = 0.f;
    __syncthreads();

    // ---- aggregation: wave = node, thread = col-pair ----
    const int node = w;
    const int cq = lane * 2;
    float2 xacc[KK];
    #pragma unroll
    for (int k = 0; k < KK; k++) xacc[k] = make_float2(0.f, 0.f);

    #pragma unroll 4
    for (int e = 0; e < NBRS; e++) {
        const int eg = node * NBRS + e;
        const unsigned mv = *(const unsigned*)&Ms[eg * 132 + cq];
        const float m0 = us2f(mv & 0xffffu);
        const float m1 = us2f(mv >> 16);
        const float* yp = Ylds + eg * 20;
        #pragma unroll
        for (int kq = 0; kq < 5; kq++) {
            float4 y = *(const float4*)(yp + kq * 4);
            const int k = kq * 4;
            xacc[k + 0].x += y.x * m0; xacc[k + 0].y += y.x * m1;
            xacc[k + 1].x += y.y * m0; xacc[k + 1].y += y.y * m1;
            xacc[k + 2].x += y.z * m0; xacc[k + 2].y += y.z * m1;
            if (kq < 4) { xacc[k + 3].x += y.w * m0; xacc[k + 3].y += y.w * m1; }
        }
    }
    const float s = 1.0f / (float)NBRS;
    const int ng = blockIdx.x * 4 + node;
    float* xp = x + (size_t)ng * (KK * CC) + cq;
    #pragma unroll
    for (int k = 0; k < KK; k++) {
        float2 old = *(const float2*)(xp + k * CC);
        old.x += xacc[k].x * s;
        old.y += xacc[k].y * s;
        *(float2*)(xp + k * CC) = old;
    }
}

// ---------------- atom logits ----------------
__global__ void k_logits(const float* __restrict__ x, const float* __restrict__ Wa,
                         const float* __restrict__ ba, float* __restrict__ out) {
    int idx = blockIdx.x * blockDim.x + threadIdx.x;
    if (idx >= NN * MAXZV) return;
    int n = idx / MAXZV, a = idx - n * MAXZV;
    float acc = ba[a];
    const float* hn = x + (size_t)n * (KK * CC);
    for (int c = 0; c < CC; c++) acc += hn[c] * Wa[c * MAXZV + a];
    out[idx] = acc;
}

// ---------------- coord_diff ----------------
__global__ void k_coord(const int* __restrict__ ei, const float* __restrict__ x,
                        const float* __restrict__ wf, const float* __restrict__ dirn,
                        float* __restrict__ out) {
    int n = blockIdx.x;
    int t = threadIdx.x;  // 64
    __shared__ float fs[NBRS];
    __shared__ float wsh[CC];
    wsh[t] = wf[t];
    wsh[t + 64] = wf[t + 64];
    __syncthreads();
    if (t < NBRS) {
        int e = n * NBRS + t;
        int sidx = ei[e];
        const float* xs = x + (size_t)sidx * (KK * CC);
        const float* xd = x + (size_t)n * (KK * CC);
        float acc = 0.0f;
        for (int c = 0; c < CC; c++) acc += (xs[c] - xd[c]) * wsh[c];
        fs[t] = acc;
    }
    __syncthreads();
    if (t < 3) {
        float acc = 0.0f;
        #pragma unroll
        for (int j = 0; j < NBRS; j++) acc += fs[j] * dirn[(size_t)(n * NBRS + j) * 3 + t];
        out[n * 3 + t] = acc;
    }
}

extern "C" void kernel_launch(void* const* d_in, const int* in_sizes, int n_in,
                              void* d_out, int out_size, void* d_ws, size_t ws_size,
                              hipStream_t stream) {
    (void)in_sizes; (void)n_in; (void)out_size; (void)ws_size;
    const float* z       = (const float*)d_in[0];
    const float* frac    = (const float*)d_in[1];
    const int*   atype   = (const int*)d_in[2];
    const float* lengths = (const float*)d_in[4];
    const float* angles  = (const float*)d_in[5];
    const int*   batch   = (const int*)d_in[6];
    const int*   ei      = (const int*)d_in[7];
    const float* emb     = (const float*)d_in[8];
    const float* zproj   = (const float*)d_in[9];
    const float* Wd      = (const float*)d_in[10];
    const float* W1      = (const float*)d_in[11];
    const float* W2      = (const float*)d_in[12];
    const float* Wa      = (const float*)d_in[13];
    const float* ba      = (const float*)d_in[14];
    const float* wf      = (const float*)d_in[15];
    float* out = (float*)d_out;

    float* ws = (float*)d_ws;
    float* pos  = ws; ws += NN * 3 + 4;          // keep 16B alignment
    float* dist = ws; ws += EE;
    float* dirn = ws; ws += EE * 3;
    float* Yv   = ws; ws += (size_t)EE * KK + 4;
    float* Yp   = ws; ws += (size_t)EE * 20;     // CSR-permuted, padded to 20
    float* zc   = ws; ws += N_CRYST * CC;
    float* x    = ws; ws += (size_t)NN * KK * CC;
    int* rowptr = (int*)ws;                       // 64*33
    int* origid = rowptr + 64 * 33 + 4;           // EE (pad so Abf is 16B-aligned)
    ushort_t* Abf  = (ushort_t*)(origid + EE);    // [E][256]: 0-127 s, 128-255 rbf
    ushort_t* WT1  = Abf + (size_t)EE * 256;      // [8][256][256]
    ushort_t* WT2  = WT1 + (size_t)NLAYERS * 256 * 256;  // [8][128][256]

    k_pos<<<NN / 256, 256, 0, stream>>>(frac, lengths, angles, batch, pos);
    k_edge<<<EE / 256, 256, 0, stream>>>(ei, pos, dist, dirn, Yv);
    k_csr<<<N_CRYST, 64, 0, stream>>>(ei, Yv, rowptr, origid, Yp);
    k_rbfA<<<(EE * NBASIS) / 256, 256, 0, stream>>>(dist, Abf);
    k_wt<<<(NLAYERS * (HIDDIM * 256 + CC * HIDDIM)) / 256, 256, 0, stream>>>(W1, Wd, W2, WT1, WT2);
    k_zc<<<(N_CRYST * CC) / 256, 256, 0, stream>>>(z, zproj, zc);
    k_xinit<<<(NN * KK * CC) / 256, 256, 0, stream>>>(atype, batch, emb, zc, x);

    for (int l = 0; l < NLAYERS; l++) {
        k_s2<<<512, 256, 0, stream>>>(rowptr, origid, Yp, x, Abf);
        k_fused<<<512, 256, 0, stream>>>(Abf,
                                         WT1 + (size_t)l * 256 * 256,
                                         WT2 + (size_t)l * CC * HIDDIM,
                                         Yv, x);
    }

    k_coord<<<NN, 64, 0, stream>>>(ei, x, wf, dirn, out);
    k_logits<<<(NN * MAXZV) / 256, 256, 0, stream>>>(x, Wa, ba, out + NN * 3);
}

// Round 4
// 527.976 us; speedup vs baseline: 1.1346x; 1.0012x over previous
//
#include <hip/hip_runtime.h>
#include <hip/hip_bf16.h>
#include <hip/hip_cooperative_groups.h>

namespace cg = cooperative_groups;

#define N_CRYST 64
#define ATOMS_PER 32
#define NN 2048
#define NBRS 20
#define EE 40960
#define CC 128
#define HIDDIM 256
#define NBASIS 128
#define NLAYERS 8
#define LMAXV 6
#define KK 19
#define MAXZV 100
#define ZDIMV 256
#define FOUR_PI_F 12.566370614359172f

typedef unsigned short ushort_t;
typedef __attribute__((ext_vector_type(8))) short short8;
typedef __attribute__((ext_vector_type(4))) float floatx4;

__device__ __forceinline__ ushort_t f2us(float f) {
    union { float f; unsigned u; } x;
    x.f = f;
    unsigned r = (x.u + 0x7fffu + ((x.u >> 16) & 1u)) >> 16;
    return (ushort_t)r;
}
__device__ __forceinline__ float us2f(unsigned u) {  // low 16 bits = bf16
    return __uint_as_float(u << 16);
}

// ---------------- lattice + positions ----------------
__global__ void k_pos(const float* __restrict__ frac, const float* __restrict__ lengths,
                      const float* __restrict__ angles, const int* __restrict__ batch,
                      float* __restrict__ pos) {
    int n = blockIdx.x * blockDim.x + threadIdx.x;
    if (n >= NN) return;
    int b = batch[n];
    float la = lengths[b * 3 + 0];
    float lb = lengths[b * 3 + 1];
    float lc = lengths[b * 3 + 2];
    const float D2R = 0.017453292519943295f;
    float aa = angles[b * 3 + 0] * D2R;
    float ab = angles[b * 3 + 1] * D2R;
    float ag = angles[b * 3 + 2] * D2R;
    float ca = cosf(aa), cb = cosf(ab), cg = cosf(ag), sg = sinf(ag);
    float v3y = (ca - cb * cg) / sg;
    float v3z = sqrtf(fmaxf(1.0f - cb * cb - v3y * v3y, 1e-8f));
    float f0 = frac[n * 3 + 0];
    float f1 = frac[n * 3 + 1];
    float f2 = frac[n * 3 + 2];
    pos[n * 3 + 0] = f0 * la + f1 * (lb * cg) + f2 * (lc * cb);
    pos[n * 3 + 1] = f1 * (lb * sg) + f2 * (lc * v3y);
    pos[n * 3 + 2] = f2 * (lc * v3z);
}

// ---------------- edge geometry ----------------
__global__ void k_edge(const int* __restrict__ ei, const float* __restrict__ pos,
                       float* __restrict__ dist, float* __restrict__ dirn,
                       float* __restrict__ Yv) {
    int e = blockIdx.x * blockDim.x + threadIdx.x;
    if (e >= EE) return;
    int s = ei[e], d = ei[EE + e];
    float vx = pos[s * 3 + 0] - pos[d * 3 + 0];
    float vy = pos[s * 3 + 1] - pos[d * 3 + 1];
    float vz = pos[s * 3 + 2] - pos[d * 3 + 2];
    float dd = sqrtf(vx * vx + vy * vy + vz * vz) + 1e-8f;
    float ix = vx / dd, iy = vy / dd, iz = vz / dd;
    dist[e] = dd;
    dirn[e * 3 + 0] = ix;
    dirn[e * 3 + 1] = iy;
    dirn[e * 3 + 2] = iz;

    float ct = iz;
    float rho = sqrtf(ix * ix + iy * iy) + 1e-12f;
    float cph = ix / rho, sph = iy / rho;
    float P0[LMAXV + 1];
    float P1[LMAXV + 1];
    P0[0] = 1.0f;
    P0[1] = ct;
    #pragma unroll
    for (int l = 2; l <= LMAXV; l++)
        P0[l] = ((2 * l - 1) * ct * P0[l - 1] - (l - 1) * P0[l - 2]) / (float)l;
    P1[0] = 0.0f;
    P1[1] = -rho;
    P1[2] = -3.0f * ct * rho;
    #pragma unroll
    for (int l = 3; l <= LMAXV; l++)
        P1[l] = ((2 * l - 1) * ct * P1[l - 1] - l * P1[l - 2]) / (float)(l - 1);

    float* Ye = Yv + (size_t)e * KK;
    Ye[0] = 0.28209479177387814f;
    #pragma unroll
    for (int l = 1; l <= LMAXV; l++) {
        float K0 = sqrtf((2 * l + 1) / FOUR_PI_F);
        float K1 = sqrtf(2.0f * (2 * l + 1) / (FOUR_PI_F * l * (l + 1)));
        Ye[3 * l - 2] = K1 * P1[l] * sph;
        Ye[3 * l - 1] = K0 * P0[l];
        Ye[3 * l]     = K1 * P1[l] * cph;
    }
}

// ---------------- CSR by source atom (layer-invariant) + permuted padded Y ----------------
__global__ void k_csr(const int* __restrict__ ei, const float* __restrict__ Yv,
                      int* __restrict__ rowptr, int* __restrict__ origid,
                      float* __restrict__ Yp) {
    int cr = blockIdx.x;  // 64 blocks x 64 threads
    int t = threadIdx.x;
    __shared__ int cnt[32], base[32];
    if (t < 32) cnt[t] = 0;
    __syncthreads();
    for (int j = t; j < 640; j += 64) {
        int a = ei[cr * 640 + j] - cr * 32;
        atomicAdd(&cnt[a], 1);
    }
    __syncthreads();
    if (t == 0) {
        int run = 0;
        for (int a = 0; a < 32; a++) {
            base[a] = run;
            rowptr[cr * 33 + a] = run;
            run += cnt[a];
        }
        rowptr[cr * 33 + 32] = run;
    }
    __syncthreads();
    if (t < 32) cnt[t] = 0;
    __syncthreads();
    for (int j = t; j < 640; j += 64) {
        int e = cr * 640 + j;
        int a = ei[e] - cr * 32;
        int slot = base[a] + atomicAdd(&cnt[a], 1);
        int p = cr * 640 + slot;
        origid[p] = e;
        float* yp = Yp + (size_t)p * 20;
        #pragma unroll
        for (int k = 0; k < KK; k++) yp[k] = Yv[(size_t)e * KK + k];
        yp[19] = 0.0f;
    }
}

// ---------------- rbf -> bf16 into A-buffer cols [128,256) (layer-invariant) ----------------
__global__ void k_rbfA(const float* __restrict__ dist, ushort_t* __restrict__ Abf) {
    int idx = blockIdx.x * blockDim.x + threadIdx.x;
    if (idx >= EE * NBASIS) return;
    int e = idx >> 7, j = idx & 127;
    const float width = 8.0f / 127.0f;
    const float invw = 127.0f / 8.0f;
    float t = (dist[e] - (float)j * width) * invw;
    Abf[(size_t)e * 256 + 128 + j] = f2us(expf(-0.5f * t * t));
}

// ---------------- weight transpose+cast ----------------
__global__ void k_wt(const float* __restrict__ W1, const float* __restrict__ Wd,
                     const float* __restrict__ W2,
                     ushort_t* __restrict__ WT1, ushort_t* __restrict__ WT2) {
    int idx = blockIdx.x * blockDim.x + threadIdx.x;
    const int n1 = NLAYERS * HIDDIM * 256;
    if (idx < n1) {
        int l = idx >> 16;
        int r = idx & 65535;
        int n = r >> 8, k = r & 255;
        float v = (k < 128) ? W1[((size_t)l * CC + k) * HIDDIM + n]
                            : Wd[((size_t)l * NBASIS + (k - 128)) * HIDDIM + n];
        WT1[idx] = f2us(v);
    } else {
        int j = idx - n1;
        if (j >= NLAYERS * CC * HIDDIM) return;
        int l = j >> 15;
        int r = j & 32767;
        int n = r >> 8, k = r & 255;
        WT2[j] = f2us(W2[((size_t)l * HIDDIM + k) * CC + n]);
    }
}

// ---------------- z @ zproj ----------------
__global__ void k_zc(const float* __restrict__ z, const float* __restrict__ zproj,
                     float* __restrict__ zc) {
    int idx = blockIdx.x * blockDim.x + threadIdx.x;
    if (idx >= N_CRYST * CC) return;
    int b = idx >> 7, c = idx & 127;
    float acc = 0.0f;
    for (int d = 0; d < ZDIMV; d++)
        acc += z[b * ZDIMV + d] * zproj[d * CC + c];
    zc[idx] = acc;
}

// ---------------- init x ----------------
__global__ void k_xinit(const int* __restrict__ atype, const int* __restrict__ batch,
                        const float* __restrict__ emb, const float* __restrict__ zc,
                        float* __restrict__ x) {
    int idx = blockIdx.x * blockDim.x + threadIdx.x;
    if (idx >= NN * KK * CC) return;
    int n = idx / (KK * CC);
    int r = idx - n * (KK * CC);
    float v = 0.0f;
    if (r < CC) v = emb[atype[n] * CC + r] + zc[batch[n] * CC + r];
    x[idx] = v;
}

// ======= device-side phase bodies (shared by mega kernel and fallback kernels) =======

struct FusedSmem {
    // GEMM1: As[80][72] @0 (11520) | Bs[256][72] @11520 (36864) -> 48384
    // GEMM2: Hs[80][264] @0 (42240) | B2s[128][72] @42240 (18432) -> 60672
    // epi:   Ms[80][132] @0 (21120) | Ylds f32 [80][20] @21120 (6400) -> 27520
    char raw[60672];
};

__device__ __forceinline__ void s_phase_body(int bid, int t,
                                             const int* __restrict__ rowptr,
                                             const int* __restrict__ origid,
                                             const float* __restrict__ Yp,
                                             const float* __restrict__ x,
                                             ushort_t* __restrict__ Abf) {
    int cr = bid >> 3;
    int cbase = (bid & 7) * 16;
    int a = t >> 3;
    int c2 = cbase + (t & 7) * 2;

    float2 xr[20];
    const float* xp = x + (size_t)(cr * 32 + a) * (KK * CC) + c2;
    #pragma unroll
    for (int k = 0; k < KK; k++) xr[k] = *(const float2*)(xp + k * CC);
    xr[19] = make_float2(0.f, 0.f);

    int i0 = rowptr[cr * 33 + a], i1 = rowptr[cr * 33 + a + 1];
    for (int i = i0; i < i1; i++) {
        int p = cr * 640 + i;
        const float* yp = Yp + (size_t)p * 20;
        float ax = 0.f, ay = 0.f;
        #pragma unroll
        for (int kq = 0; kq < 5; kq++) {
            float4 y = *(const float4*)(yp + kq * 4);
            float2 x0 = xr[kq * 4 + 0], x1 = xr[kq * 4 + 1];
            float2 x2 = xr[kq * 4 + 2], x3 = xr[kq * 4 + 3];
            ax += y.x * x0.x + y.y * x1.x + y.z * x2.x + y.w * x3.x;
            ay += y.x * x0.y + y.y * x1.y + y.z * x2.y + y.w * x3.y;
        }
        int e = origid[p];
        unsigned pk = (unsigned)f2us(ax) | (((unsigned)f2us(ay)) << 16);
        *(unsigned*)&Abf[(size_t)e * 256 + c2] = pk;
    }
}

__device__ __forceinline__ void fused_body(int bid, int t, char* smraw,
                                           const ushort_t* __restrict__ Abf,
                                           const ushort_t* __restrict__ WT1,
                                           const ushort_t* __restrict__ WT2,
                                           const float* __restrict__ Yv,
                                           float* __restrict__ x) {
    ushort_t* As  = (ushort_t*)smraw;
    ushort_t* Bs  = (ushort_t*)(smraw + 11520);
    ushort_t* Hs  = (ushort_t*)smraw;
    ushort_t* B2s = (ushort_t*)(smraw + 42240);
    ushort_t* Ms  = (ushort_t*)smraw;
    float*   Ylds = (float*)(smraw + 21120);

    const int w = t >> 6, lane = t & 63;
    const int quad = lane >> 4, lrow = lane & 15;
    const int e0 = bid * 80;
    const ushort_t* Ab = Abf + (size_t)e0 * 256;
    const int a0r = t >> 3,         ac = (t & 7) * 8;
    const int a1r = (t + 256) >> 3;
    const int a2r = (t + 512) >> 3;           // valid iff t < 128
    const int brow = t >> 3, bcol = (t & 7) * 8;

    floatx4 acc[5][4];
    #pragma unroll
    for (int mi = 0; mi < 5; mi++)
        #pragma unroll
        for (int ni = 0; ni < 4; ni++) acc[mi][ni] = (floatx4){0.f, 0.f, 0.f, 0.f};

    short8 arg0, arg1, arg2, brg[8];

    // prologue: chunk 0 of A and B
    arg0 = *(const short8*)(Ab + a0r * 256 + ac);
    arg1 = *(const short8*)(Ab + a1r * 256 + ac);
    if (t < 128) arg2 = *(const short8*)(Ab + a2r * 256 + ac);
    #pragma unroll
    for (int i = 0; i < 8; i++)
        brg[i] = *(const short8*)(WT1 + (size_t)(i * 32 + brow) * 256 + bcol);
    *(short8*)&As[a0r * 72 + ac] = arg0;
    *(short8*)&As[a1r * 72 + ac] = arg1;
    if (t < 128) *(short8*)&As[a2r * 72 + ac] = arg2;
    #pragma unroll
    for (int i = 0; i < 8; i++) *(short8*)&Bs[(i * 32 + brow) * 72 + bcol] = brg[i];
    __syncthreads();

    // GEMM1 K-loop: prefetch chunk c+1 into regs, MFMA chunk c
    #pragma unroll
    for (int c = 0; c < 4; c++) {
        if (c < 3) {
            const int k0 = (c + 1) * 64;
            arg0 = *(const short8*)(Ab + a0r * 256 + k0 + ac);
            arg1 = *(const short8*)(Ab + a1r * 256 + k0 + ac);
            if (t < 128) arg2 = *(const short8*)(Ab + a2r * 256 + k0 + ac);
            #pragma unroll
            for (int i = 0; i < 8; i++)
                brg[i] = *(const short8*)(WT1 + (size_t)(i * 32 + brow) * 256 + k0 + bcol);
        }
        #pragma unroll
        for (int ks = 0; ks < 2; ks++) {
            const int kk = ks * 32 + quad * 8;
            short8 af[5];
            #pragma unroll
            for (int mi = 0; mi < 5; mi++)
                af[mi] = *(const short8*)&As[(mi * 16 + lrow) * 72 + kk];
            #pragma unroll
            for (int ni = 0; ni < 4; ni++) {
                short8 bf = *(const short8*)&Bs[(w * 64 + ni * 16 + lrow) * 72 + kk];
                #pragma unroll
                for (int mi = 0; mi < 5; mi++)
                    acc[mi][ni] = __builtin_amdgcn_mfma_f32_16x16x32_bf16(
                        af[mi], bf, acc[mi][ni], 0, 0, 0);
            }
        }
        __syncthreads();
        if (c < 3) {
            *(short8*)&As[a0r * 72 + ac] = arg0;
            *(short8*)&As[a1r * 72 + ac] = arg1;
            if (t < 128) *(short8*)&As[a2r * 72 + ac] = arg2;
            #pragma unroll
            for (int i = 0; i < 8; i++) *(short8*)&Bs[(i * 32 + brow) * 72 + bcol] = brg[i];
            __syncthreads();
        }
    }

    // silu -> Hs; prefetch B2 chunk 0 + Y tile
    short8 b2rg[4];
    #pragma unroll
    for (int i = 0; i < 4; i++)
        b2rg[i] = *(const short8*)(WT2 + (size_t)(i * 32 + brow) * 256 + bcol);
    float yrg[6];
    const float* Yb = Yv + (size_t)e0 * KK;
    #pragma unroll
    for (int j = 0; j < 6; j++) {
        int i = t + j * 256;
        yrg[j] = (i < 80 * KK) ? Yb[i] : 0.f;
    }
    #pragma unroll
    for (int mi = 0; mi < 5; mi++) {
        const int row = mi * 16 + quad * 4;
        #pragma unroll
        for (int ni = 0; ni < 4; ni++) {
            const int col = w * 64 + ni * 16 + lrow;
            #pragma unroll
            for (int r = 0; r < 4; r++) {
                float v = acc[mi][ni][r];
                v = v * __builtin_amdgcn_rcpf(1.0f + __expf(-v));
                Hs[(row + r) * 264 + col] = f2us(v);
            }
        }
    }
    #pragma unroll
    for (int i = 0; i < 4; i++) *(short8*)&B2s[(i * 32 + brow) * 72 + bcol] = b2rg[i];
    __syncthreads();

    // GEMM2: m = silu(h) @ W2T, K chunked over hidden 256
    floatx4 macc[5][2];
    #pragma unroll
    for (int mi = 0; mi < 5; mi++)
        #pragma unroll
        for (int ni = 0; ni < 2; ni++) macc[mi][ni] = (floatx4){0.f, 0.f, 0.f, 0.f};

    #pragma unroll
    for (int c = 0; c < 4; c++) {
        if (c < 3) {
            const int k0 = (c + 1) * 64;
            #pragma unroll
            for (int i = 0; i < 4; i++)
                b2rg[i] = *(const short8*)(WT2 + (size_t)(i * 32 + brow) * 256 + k0 + bcol);
        }
        #pragma unroll
        for (int ks = 0; ks < 2; ks++) {
            const int kk = ks * 32 + quad * 8;
            short8 af[5];
            #pragma unroll
            for (int mi = 0; mi < 5; mi++)
                af[mi] = *(const short8*)&Hs[(mi * 16 + lrow) * 264 + c * 64 + kk];
            #pragma unroll
            for (int ni = 0; ni < 2; ni++) {
                short8 bf = *(const short8*)&B2s[(w * 32 + ni * 16 + lrow) * 72 + kk];
                #pragma unroll
                for (int mi = 0; mi < 5; mi++)
                    macc[mi][ni] = __builtin_amdgcn_mfma_f32_16x16x32_bf16(
                        af[mi], bf, macc[mi][ni], 0, 0, 0);
            }
        }
        __syncthreads();
        if (c < 3) {
            #pragma unroll
            for (int i = 0; i < 4; i++) *(short8*)&B2s[(i * 32 + brow) * 72 + bcol] = b2rg[i];
            __syncthreads();
        }
    }

    // macc -> Ms bf16 [80][132]; Y regs -> Ylds
    #pragma unroll
    for (int mi = 0; mi < 5; mi++) {
        const int row = mi * 16 + quad * 4;
        #pragma unroll
        for (int ni = 0; ni < 2; ni++) {
            const int col = w * 32 + ni * 16 + lrow;
            #pragma unroll
            for (int r = 0; r < 4; r++)
                Ms[(row + r) * 132 + col] = f2us(macc[mi][ni][r]);
        }
    }
    #pragma unroll
    for (int j = 0; j < 6; j++) {
        int i = t + j * 256;
        if (i < 80 * KK) Ylds[(i / KK) * 20 + (i % KK)] = yrg[j];
    }
    if (t < 80) Ylds[t * 20 + 19] = 0.f;
    __syncthreads();

    // aggregation: wave = node, thread = col-pair
    const int node = w;
    const int cq = lane * 2;
    float2 xacc[KK];
    #pragma unroll
    for (int k = 0; k < KK; k++) xacc[k] = make_float2(0.f, 0.f);

    #pragma unroll 4
    for (int e = 0; e < NBRS; e++) {
        const int eg = node * NBRS + e;
        const unsigned mv = *(const unsigned*)&Ms[eg * 132 + cq];
        const float m0 = us2f(mv & 0xffffu);
        const float m1 = us2f(mv >> 16);
        const float* yp = Ylds + eg * 20;
        #pragma unroll
        for (int kq = 0; kq < 5; kq++) {
            float4 y = *(const float4*)(yp + kq * 4);
            const int k = kq * 4;
            xacc[k + 0].x += y.x * m0; xacc[k + 0].y += y.x * m1;
            xacc[k + 1].x += y.y * m0; xacc[k + 1].y += y.y * m1;
            xacc[k + 2].x += y.z * m0; xacc[k + 2].y += y.z * m1;
            if (kq < 4) { xacc[k + 3].x += y.w * m0; xacc[k + 3].y += y.w * m1; }
        }
    }
    const float s = 1.0f / (float)NBRS;
    const int ng = bid * 4 + node;
    float* xp = x + (size_t)ng * (KK * CC) + cq;
    #pragma unroll
    for (int k = 0; k < KK; k++) {
        float2 old = *(const float2*)(xp + k * CC);
        old.x += xacc[k].x * s;
        old.y += xacc[k].y * s;
        *(float2*)(xp + k * CC) = old;
    }
}

// ---------------- fallback: standalone per-layer kernels (verified round-1 path) --------
__global__ __launch_bounds__(256) void k_s2(const int* __restrict__ rowptr,
                                            const int* __restrict__ origid,
                                            const float* __restrict__ Yp,
                                            const float* __restrict__ x,
                                            ushort_t* __restrict__ Abf) {
    s_phase_body(blockIdx.x, threadIdx.x, rowptr, origid, Yp, x, Abf);
}

__global__ __launch_bounds__(256, 2) void k_fused(const ushort_t* __restrict__ Abf,
                                                  const ushort_t* __restrict__ WT1,
                                                  const ushort_t* __restrict__ WT2,
                                                  const float* __restrict__ Yv,
                                                  float* __restrict__ x) {
    __shared__ FusedSmem sm;
    fused_body(blockIdx.x, threadIdx.x, sm.raw, Abf, WT1, WT2, Yv, x);
}

// ================= cooperative mega-kernel: 8 layers of (s-phase ; fused) =================
// grid 512 x 256, 2 blocks/CU (LDS 60672 x2 = 121 KB < 160 KB, VGPR <= 256).
// Explicit __threadfence() (agent-scope) around each grid sync guarantees cross-XCD
// visibility of Abf / x writes even if cg's internal fences are insufficient on gfx950.
__global__ __launch_bounds__(256, 2) void k_mega(const int* __restrict__ rowptr,
                                                 const int* __restrict__ origid,
                                                 const float* __restrict__ Yp,
                                                 float* __restrict__ x,
                                                 ushort_t* __restrict__ Abf,
                                                 const ushort_t* __restrict__ WT1b,
                                                 const ushort_t* __restrict__ WT2b,
                                                 const float* __restrict__ Yv) {
    cg::grid_group gg = cg::this_grid();
    __shared__ FusedSmem sm;
    const int t = threadIdx.x;
    const int bid = blockIdx.x;

    for (int l = 0; l < NLAYERS; l++) {
        s_phase_body(bid, t, rowptr, origid, Yp, x, Abf);
        __threadfence();   // release: drain Abf writes past XCD L2
        gg.sync();
        __threadfence();   // acquire: invalidate stale L1/L2 before reading Abf
        fused_body(bid, t, sm.raw, Abf,
                   WT1b + (size_t)l * 256 * 256,
                   WT2b + (size_t)l * CC * HIDDIM,
                   Yv, x);
        __threadfence();   // release: drain x writes
        gg.sync();
        __threadfence();   // acquire: before next layer's x reads
    }
}

// ---------------- atom logits ----------------
__global__ void k_logits(const float* __restrict__ x, const float* __restrict__ Wa,
                         const float* __restrict__ ba, float* __restrict__ out) {
    int idx = blockIdx.x * blockDim.x + threadIdx.x;
    if (idx >= NN * MAXZV) return;
    int n = idx / MAXZV, a = idx - n * MAXZV;
    float acc = ba[a];
    const float* hn = x + (size_t)n * (KK * CC);
    for (int c = 0; c < CC; c++) acc += hn[c] * Wa[c * MAXZV + a];
    out[idx] = acc;
}

// ---------------- coord_diff ----------------
__global__ void k_coord(const int* __restrict__ ei, const float* __restrict__ x,
                        const float* __restrict__ wf, const float* __restrict__ dirn,
                        float* __restrict__ out) {
    int n = blockIdx.x;
    int t = threadIdx.x;  // 64
    __shared__ float fs[NBRS];
    __shared__ float wsh[CC];
    wsh[t] = wf[t];
    wsh[t + 64] = wf[t + 64];
    __syncthreads();
    if (t < NBRS) {
        int e = n * NBRS + t;
        int sidx = ei[e];
        const float* xs = x + (size_t)sidx * (KK * CC);
        const float* xd = x + (size_t)n * (KK * CC);
        float acc = 0.0f;
        for (int c = 0; c < CC; c++) acc += (xs[c] - xd[c]) * wsh[c];
        fs[t] = acc;
    }
    __syncthreads();
    if (t < 3) {
        float acc = 0.0f;
        #pragma unroll
        for (int j = 0; j < NBRS; j++) acc += fs[j] * dirn[(size_t)(n * NBRS + j) * 3 + t];
        out[n * 3 + t] = acc;
    }
}

extern "C" void kernel_launch(void* const* d_in, const int* in_sizes, int n_in,
                              void* d_out, int out_size, void* d_ws, size_t ws_size,
                              hipStream_t stream) {
    (void)in_sizes; (void)n_in; (void)out_size; (void)ws_size;
    const float* z       = (const float*)d_in[0];
    const float* frac    = (const float*)d_in[1];
    const int*   atype   = (const int*)d_in[2];
    const float* lengths = (const float*)d_in[4];
    const float* angles  = (const float*)d_in[5];
    const int*   batch   = (const int*)d_in[6];
    const int*   ei      = (const int*)d_in[7];
    const float* emb     = (const float*)d_in[8];
    const float* zproj   = (const float*)d_in[9];
    const float* Wd      = (const float*)d_in[10];
    const float* W1      = (const float*)d_in[11];
    const float* W2      = (const float*)d_in[12];
    const float* Wa      = (const float*)d_in[13];
    const float* ba      = (const float*)d_in[14];
    const float* wf      = (const float*)d_in[15];
    float* out = (float*)d_out;

    float* ws = (float*)d_ws;
    float* pos  = ws; ws += NN * 3 + 4;          // keep 16B alignment
    float* dist = ws; ws += EE;
    float* dirn = ws; ws += EE * 3;
    float* Yv   = ws; ws += (size_t)EE * KK + 4;
    float* Yp   = ws; ws += (size_t)EE * 20;     // CSR-permuted, padded to 20
    float* zc   = ws; ws += N_CRYST * CC;
    float* x    = ws; ws += (size_t)NN * KK * CC;
    int* rowptr = (int*)ws;                       // 64*33
    int* origid = rowptr + 64 * 33 + 4;           // EE (pad so Abf is 16B-aligned)
    ushort_t* Abf  = (ushort_t*)(origid + EE);    // [E][256]: 0-127 s, 128-255 rbf
    ushort_t* WT1  = Abf + (size_t)EE * 256;      // [8][256][256]
    ushort_t* WT2  = WT1 + (size_t)NLAYERS * 256 * 256;  // [8][128][256]

    k_pos<<<NN / 256, 256, 0, stream>>>(frac, lengths, angles, batch, pos);
    k_edge<<<EE / 256, 256, 0, stream>>>(ei, pos, dist, dirn, Yv);
    k_csr<<<N_CRYST, 64, 0, stream>>>(ei, Yv, rowptr, origid, Yp);
    k_rbfA<<<(EE * NBASIS) / 256, 256, 0, stream>>>(dist, Abf);
    k_wt<<<(NLAYERS * (HIDDIM * 256 + CC * HIDDIM)) / 256, 256, 0, stream>>>(W1, Wd, W2, WT1, WT2);
    k_zc<<<(N_CRYST * CC) / 256, 256, 0, stream>>>(z, zproj, zc);
    k_xinit<<<(NN * KK * CC) / 256, 256, 0, stream>>>(atype, batch, emb, zc, x);

    // --- layer loop: cooperative mega-kernel if supported + co-resident, else fallback ---
    static int coop_ok = -1;
    if (coop_ok < 0) {
        int dev_coop = 0;
        (void)hipDeviceGetAttribute(&dev_coop, hipDeviceAttributeCooperativeLaunch, 0);
        int maxb = 0;
        (void)hipOccupancyMaxActiveBlocksPerMultiprocessor(&maxb, k_mega, 256, 0);
        int ncu = 0;
        (void)hipDeviceGetAttribute(&ncu, hipDeviceAttributeMultiprocessorCount, 0);
        coop_ok = (dev_coop && (long)maxb * (long)ncu >= 512) ? 1 : 0;
    }

    bool done = false;
    if (coop_ok == 1) {
        const int* p_rowptr = rowptr;
        const int* p_origid = origid;
        const float* p_Yp = Yp;
        float* p_x = x;
        ushort_t* p_Abf = Abf;
        const ushort_t* p_WT1 = WT1;
        const ushort_t* p_WT2 = WT2;
        const float* p_Yv = Yv;
        void* args[] = {(void*)&p_rowptr, (void*)&p_origid, (void*)&p_Yp, (void*)&p_x,
                        (void*)&p_Abf, (void*)&p_WT1, (void*)&p_WT2, (void*)&p_Yv};
        hipError_t ce = hipLaunchCooperativeKernel((void*)k_mega, dim3(512), dim3(256),
                                                   args, 0, stream);
        done = (ce == hipSuccess);
        if (!done) coop_ok = 0;  // don't retry on later invocations
    }
    if (!done) {
        for (int l = 0; l < NLAYERS; l++) {
            k_s2<<<512, 256, 0, stream>>>(rowptr, origid, Yp, x, Abf);
            k_fused<<<512, 256, 0, stream>>>(Abf,
                                             WT1 + (size_t)l * 256 * 256,
                                             WT2 + (size_t)l * CC * HIDDIM,
                                             Yv, x);
        }
    }

    k_coord<<<NN, 64, 0, stream>>>(ei, x, wf, dirn, out);
    k_logits<<<(NN * MAXZV) / 256, 256, 0, stream>>>(x, Wa, ba, out + NN * 3);
}